// Round 12
// baseline (1480.314 us; speedup 1.0000x reference)
//
#include <hip/hip_runtime.h>
#include <cstdint>
#include <cstddef>

// CTC-CRF logZ: S=1024, NZ=5. Consumer recursion reads PRECOMPUTED fp16
// E = exp2(K*m) (10 KB/step, half of fp32 scores) -> attacks the measured
// per-CU delivery ceiling (R9: 20 KB/step @ 26.7 B/cyc = 768 cyc/step).
// R11 failed because nontemporal E-stores streamed to HBM (WRITE 640MB).
// Now: producers (192 blocks) nt-LOAD scores, normal-store E into a W=64
// ring in d_ws (20 MB total -> L3-resident), release-flag per 16-step
// chunk. Consumers (32 blocks) gate each chunk with an agent ACQUIRE in
// every wave (buffer_inv -> placement-independent coherence; E comes from
// L3), 8-set register pipeline (lookahead 8 steps covers L3 latency),
// deadbeat pow2 renorm, zero transcendentals in the hot loop.
// All blocks LDS-padded -> 1 block/CU. Fallback = exact R9 (640 us).

#define NB 32
#define SD 1024
#define CD 5120
#define WR 64
#define WMASK 63
#define DONE_S 0x7fffffff
#define AHEAD 24
#define CHUNK 8

typedef float f4a __attribute__((ext_vector_type(4), aligned(4)));
typedef unsigned short u16;
typedef u16 us4 __attribute__((ext_vector_type(4), aligned(8)));

__device__ __forceinline__ float fexp2(float x) { return __builtin_amdgcn_exp2f(x); }
__device__ __forceinline__ float flog2(float x) { return __builtin_amdgcn_logf(x); }
__device__ __forceinline__ u16 f2h(float f) { _Float16 h = (_Float16)f; return __builtin_bit_cast(u16, h); }
__device__ __forceinline__ float h2f(u16 b) { return (float)__builtin_bit_cast(_Float16, b); }

template <int CTRL>
__device__ __forceinline__ float dppq(float v) {
  return __int_as_float(
      __builtin_amdgcn_update_dpp(0, __float_as_int(v), CTRL, 0xF, 0xF, true));
}

// ws ints: [0..2047] prog (n*64), [2048..6143] flags (n*128+c). byte 65536+:
// EA = 32*WR*4096 u16, then EB = 32*WR*1024 u16.
__global__ void init_ws(int* ws) {
  const int i = threadIdx.x;
#pragma unroll
  for (int k = 0; k < 6; ++k) ws[i + (k << 10)] = 0;
}

__global__ void __launch_bounds__(1024) ctc_fused(const float* __restrict__ scores,
                                                  float* __restrict__ out,
                                                  int* __restrict__ ws, int T) {
  __shared__ float ap[2 * SD];
  __shared__ float red[16];
  __shared__ float pad[19456];   // force 1 block/CU
  __shared__ int pmsg;

  const int bid = blockIdx.x;
  const int u = threadIdx.x;
  if (T < 0) { pad[u] = 1.f; out[0] = pad[u ^ 1]; }

  int* prog = ws;
  int* flags = ws + 2048;
  u16* EA = (u16*)((char*)ws + 65536);
  u16* EB = EA + (size_t)32 * WR * 4096;
  const size_t tstr = (size_t)NB * CD;
  const int NC = (T + 15) >> 4;

  if (bid >= NB) {
    // ------------------------------ producer ------------------------------
    const int h = bid - NB;
    const int n = h & 31;
    const int k = h >> 5;                    // 0..5
    u16* EAw = EA + (size_t)n * WR * 4096;
    u16* EBw = EB + (size_t)n * WR * 1024;
    const float K = 1.44269504088896340736f;
    for (int c = k; (c << 4) < T; c += 6) {
      const int t0 = c << 4;
      for (;;) {
        if (u == 0) {
          int p = __hip_atomic_load(&prog[n << 6], __ATOMIC_RELAXED, __HIP_MEMORY_SCOPE_AGENT);
          pmsg = (p == DONE_S) ? 2 : ((t0 + 15 < p + WR) ? 1 : 0);
        }
        __syncthreads();
        const int st = pmsg;
        __syncthreads();
        if (st == 2) return;
        if (st == 1) break;
        __builtin_amdgcn_s_sleep(16);
      }
      const float* sp = scores + (size_t)n * CD + (size_t)t0 * tstr + (size_t)u * 5;
      const int lim = (T - t0 < 16) ? (T - t0) : 16;
#define PEMIT(RA, RB, S)                                                     \
  {                                                                          \
    const int slot = (t0 + (S)) & WMASK;                                     \
    us4 o;                                                                   \
    o.x = f2h(fexp2(RA.x * K)); o.y = f2h(fexp2(RA.y * K));                  \
    o.z = f2h(fexp2(RA.z * K)); o.w = f2h(fexp2(RA.w * K));                  \
    *(us4*)(EAw + (size_t)slot * 4096 + (u << 2)) = o;                       \
    EBw[(size_t)slot * 1024 + u] = f2h(fexp2(RB * K));                       \
  }
      f4a ra0, ra1; float rb0, rb1;
      ra0 = __builtin_nontemporal_load((const f4a*)sp);
      rb0 = __builtin_nontemporal_load(sp + 4);
      sp += tstr;
      if (lim > 1) {
        ra1 = __builtin_nontemporal_load((const f4a*)sp);
        rb1 = __builtin_nontemporal_load(sp + 4);
      }
      sp += tstr;
      int s = 0;
      for (;;) {
        PEMIT(ra0, rb0, s);
        if (s + 2 < lim) {
          ra0 = __builtin_nontemporal_load((const f4a*)sp);
          rb0 = __builtin_nontemporal_load(sp + 4);
          sp += tstr;
        }
        if (++s >= lim) break;
        PEMIT(ra1, rb1, s);
        if (s + 2 < lim) {
          ra1 = __builtin_nontemporal_load((const f4a*)sp);
          rb1 = __builtin_nontemporal_load(sp + 4);
          sp += tstr;
        }
        if (++s >= lim) break;
      }
#undef PEMIT
      __syncthreads();  // drains ALL waves' stores (vmcnt0 before barrier)
      if (u == 0)
        __hip_atomic_store(&flags[(n << 7) + c], 1, __ATOMIC_RELEASE, __HIP_MEMORY_SCOPE_AGENT);
    }
    return;
  }

  // ------------------------------- consumer -------------------------------
  {
    const int n = bid;
    const int lane = u & 63;
    const int wid = u >> 6;
    const int p = u >> 2, c = u & 3;
    const int rdoff = (c << 8) | (p ^ (c << 3));
    const int wroff = u ^ ((u & 0x300) >> 5);

    ap[u] = 1.f; ap[SD + u] = 1.f;
    float a_cur = 1.f;
    int cacc = 0;
    const float LN2 = 0.69314718055994530942f;

    const u16* EAr = EA + (size_t)n * WR * 4096;
    const u16* EBr = EB + (size_t)n * WR * 1024;

    // Wait for chunk flag; then EVERY wave does an agent ACQUIRE load
    // (emits buffer_inv) so subsequent E loads can't hit stale L1/L2.
    auto wait_flag = [&](int cidx) {
      for (;;) {
        if (u == 0)
          pmsg = __hip_atomic_load(&flags[(n << 7) + cidx], __ATOMIC_RELAXED, __HIP_MEMORY_SCOPE_AGENT);
        asm volatile("s_waitcnt lgkmcnt(0)\n\ts_barrier" ::: "memory");
        const int f = pmsg;
        asm volatile("s_barrier" ::: "memory");
        if (f) break;
        __builtin_amdgcn_s_sleep(2);
      }
      (void)__hip_atomic_load(&flags[(n << 7) + cidx], __ATOMIC_ACQUIRE, __HIP_MEMORY_SCOPE_AGENT);
    };

    auto LD1 = [&](int tt, us4& qa, u16& qb) {
      const int tc = tt < T ? tt : T - 1;
      const int slot = tc & WMASK;
      qa = *(const us4*)(EAr + (size_t)slot * 4096 + (u << 2));  // dwordx2
      qb = EBr[(size_t)slot * 1024 + u];
    };

    auto CP = [&](int t, const us4& qa, u16 qb) {
      const int rb = ((t + 1) & 1) << 10;
      const float vr = ap[rb + rdoff];
      const float R = ap[rb];
      const float p0 = dppq<0x00>(vr);
      const float p1 = dppq<0x55>(vr);
      const float p2 = dppq<0xAA>(vr);
      const float p3 = dppq<0xFF>(vr);
      float s = h2f(qa.x) * a_cur;
      s = __builtin_fmaf(h2f(qa.y), p0, s);
      s = __builtin_fmaf(h2f(qa.z), p1, s);
      s = __builtin_fmaf(h2f(qa.w), p2, s);
      s = __builtin_fmaf(h2f(qb),   p3, s);
      const int eR = (__float_as_int(R) >> 23) & 0xFF;   // deadbeat renorm
      cacc += eR - 127;
      s *= __int_as_float((254 - eR) << 23);
      a_cur = s;
      ap[((t & 1) << 10) + wroff] = s;
      if (((t & 3) == 0) && (u == 0))
        __hip_atomic_store(&prog[n << 6], t, __ATOMIC_RELAXED, __HIP_MEMORY_SCOPE_AGENT);
      asm volatile("s_waitcnt lgkmcnt(0)\n\ts_barrier" ::: "memory");
    };

    us4 qa0, qa1, qa2, qa3, qa4, qa5, qa6, qa7;
    u16 qb0, qb1, qb2, qb3, qb4, qb5, qb6, qb7;
    wait_flag(0);
    LD1(0, qa0, qb0); LD1(1, qa1, qb1); LD1(2, qa2, qb2); LD1(3, qa3, qb3);
    LD1(4, qa4, qb4); LD1(5, qa5, qb5); LD1(6, qa6, qb6); LD1(7, qa7, qb7);
    asm volatile("s_waitcnt lgkmcnt(0)\n\ts_barrier" ::: "memory");  // ap init

    int t = 0;
    for (int cb = 0; cb < NC; ++cb) {
      if (cb + 1 < NC) wait_flag(cb + 1);   // covers loads into chunk cb+1
#define STEP(SS) if (t < T) { CP(t, qa##SS, qb##SS); LD1(t + 8, qa##SS, qb##SS); ++t; }
      STEP(0) STEP(1) STEP(2) STEP(3) STEP(4) STEP(5) STEP(6) STEP(7)
      STEP(0) STEP(1) STEP(2) STEP(3) STEP(4) STEP(5) STEP(6) STEP(7)
#undef STEP
    }

    if (u == 0)
      __hip_atomic_store(&prog[n << 6], DONE_S, __ATOMIC_RELAXED, __HIP_MEMORY_SCOPE_AGENT);

    float v = a_cur;
#pragma unroll
    for (int d = 1; d < 64; d <<= 1) v += __shfl_xor(v, d, 64);
    if (lane == 0) red[wid] = v;
    __syncthreads();
    if (u == 0) {
      float ssum = red[0];
#pragma unroll
      for (int i = 1; i < 16; ++i) ssum += red[i];
      out[n] = LN2 * ((float)cacc + flog2(ssum));
    }
  }
}

// ------------------------------ fallback = exact R9 -------------------------
__global__ void __launch_bounds__(1024) ctc_base(const float* __restrict__ scores,
                                                 float* __restrict__ out,
                                                 int* __restrict__ prog, int T) {
  __shared__ float ap[2 * SD];
  __shared__ float red[16];
  __shared__ float pad[19456];
  __shared__ int pmsg;

  const int bid = blockIdx.x;
  const int u = threadIdx.x;
  if (T < 0) { pad[u] = 1.f; out[0] = pad[u ^ 1]; }
  const size_t tstr = (size_t)NB * CD;

  if (bid >= NB) {
    const int h = bid - NB;
    const int n = h & 31;
    const int parity = h >> 5;
    const float* base = scores + (size_t)n * CD;
    float acc = 0.f;
    for (int c = parity; c * CHUNK < T; c += 2) {
      const int t0 = c * CHUNK;
      int p;
      for (;;) {
        if (u == 0)
          pmsg = __hip_atomic_load(&prog[n * 64], __ATOMIC_RELAXED, __HIP_MEMORY_SCOPE_AGENT);
        __syncthreads();
        p = pmsg;
        __syncthreads();
        if (p == DONE_S || t0 < p + AHEAD) break;
        __builtin_amdgcn_s_sleep(8);
      }
      if (p == DONE_S) break;
      if (t0 + CHUNK <= p) continue;
      if (u < 320) {
        const float* cb = base + (size_t)t0 * tstr + (size_t)u * 16;
        const int lim = (T - t0 < CHUNK) ? (T - t0) : CHUNK;
        for (int s = 0; s < lim; ++s) { acc += *cb; cb += tstr; }
      }
    }
    asm volatile("" ::"v"(acc));
    return;
  }

  const int n = bid;
  const int lane = u & 63;
  const int wid = u >> 6;
  const int p = u >> 2, c = u & 3;
  const int rdoff = (c << 8) | (p ^ (c << 3));
  const int wroff = u ^ ((u & 0x300) >> 5);

  ap[u] = 1.f; ap[SD + u] = 1.f;
  float a_cur = 1.f;
  float nLf = 0.f;
  int Lnext = 0, cacc = 0;
  const float K = 1.44269504088896340736f;
  const float LN2 = 0.69314718055994530942f;
  const float* sn = scores + (size_t)n * CD + (size_t)u * 5;
  const size_t str4 = 4 * tstr;

  auto CP = [&](int t, const f4a& qa, float qb) {
    const int rb = ((t + 1) & 1) * SD;
    const float vr = ap[rb + rdoff];
    const float R = ap[rb];
    const float p0 = dppq<0x00>(vr);
    const float p1 = dppq<0x55>(vr);
    const float p2 = dppq<0xAA>(vr);
    const float p3 = dppq<0xFF>(vr);
    float e0 = fexp2(__builtin_fmaf(qa.x, K, nLf));
    float e1 = fexp2(__builtin_fmaf(qa.y, K, nLf));
    float e2 = fexp2(__builtin_fmaf(qa.z, K, nLf));
    float e3 = fexp2(__builtin_fmaf(qa.w, K, nLf));
    float e4 = fexp2(__builtin_fmaf(qb,   K, nLf));
    float s = e0 * a_cur;
    s = __builtin_fmaf(e1, p0, s);
    s = __builtin_fmaf(e2, p1, s);
    s = __builtin_fmaf(e3, p2, s);
    s = __builtin_fmaf(e4, p3, s);
    a_cur = s;
    cacc += Lnext;
    ap[(t & 1) * SD + wroff] = s;
    const int xb = ((__float_as_int(R) >> 23) & 0xFF) - 127;
    Lnext = xb >> 2;
    nLf = (float)(-Lnext);
    if (((t & 3) == 0) && (u == 0))
      __hip_atomic_store(&prog[n * 64], t, __ATOMIC_RELAXED, __HIP_MEMORY_SCOPE_AGENT);
    asm volatile("s_waitcnt lgkmcnt(0)\n\ts_barrier" ::: "memory");
  };

#define PRO(cc)                                                             \
  const float* P##cc = sn + (size_t)((cc) < T ? (cc) : T - 1) * tstr;       \
  f4a qa##cc = *(const f4a*)P##cc;                                          \
  float qb##cc = P##cc[4];                                                  \
  P##cc += str4;
  PRO(0) PRO(1) PRO(2) PRO(3)
#undef PRO
  __syncthreads();
#define RL(cc)                                                              \
  qa##cc = *(const f4a*)P##cc;                                              \
  qb##cc = P##cc[4];                                                        \
  P##cc += str4;
  int t = 0;
  for (; t + 8 <= T; t += 4) {
    CP(t + 0, qa0, qb0); RL(0)
    CP(t + 1, qa1, qb1); RL(1)
    CP(t + 2, qa2, qb2); RL(2)
    CP(t + 3, qa3, qb3); RL(3)
  }
#undef RL
#define EPI1(cc)                                                            \
  if (t + (cc) < T) {                                                       \
    CP(t + (cc), qa##cc, qb##cc);                                           \
    if (t + 4 + (cc) < T) { qa##cc = *(const f4a*)P##cc; qb##cc = P##cc[4]; }\
  }
  EPI1(0) EPI1(1) EPI1(2) EPI1(3)
#undef EPI1
  t += 4;
#define EPI2(cc) if (t + (cc) < T) CP(t + (cc), qa##cc, qb##cc);
  EPI2(0) EPI2(1) EPI2(2) EPI2(3)
#undef EPI2

  if (u == 0)
    __hip_atomic_store(&prog[n * 64], DONE_S, __ATOMIC_RELAXED, __HIP_MEMORY_SCOPE_AGENT);

  float v = a_cur;
#pragma unroll
  for (int d = 1; d < 64; d <<= 1) v += __shfl_xor(v, d, 64);
  if (lane == 0) red[wid] = v;
  __syncthreads();
  if (u == 0) {
    float ssum = red[0];
#pragma unroll
    for (int i = 1; i < 16; ++i) ssum += red[i];
    out[n] = LN2 * ((float)cacc + flog2(ssum));
  }
}

extern "C" void kernel_launch(void* const* d_in, const int* in_sizes, int n_in,
                              void* d_out, int out_size, void* d_ws, size_t ws_size,
                              hipStream_t stream) {
  const float* scores = (const float*)d_in[0];
  float* out = (float*)d_out;
  int* ws = (int*)d_ws;
  const long long tot = (long long)in_sizes[0];
  const int T = (int)(tot / ((long long)NB * CD));

  const size_t need = 65536 + (size_t)32 * WR * 10240;  // ~21 MB
  init_ws<<<dim3(1), dim3(1024), 0, stream>>>(ws);
  if (ws_size >= need && T <= 2048 && T >= 20) {
    ctc_fused<<<dim3(224), dim3(1024), 0, stream>>>(scores, out, ws, T);
  } else {
    ctc_base<<<dim3(96), dim3(1024), 0, stream>>>(scores, out, ws, T);
  }
}

// Round 13
// 1082.049 us; speedup vs baseline: 1.3681x; 1.3681x over previous
//
#include <hip/hip_runtime.h>
#include <cstdint>
#include <cstddef>

// CTC-CRF logZ: S=1024, NZ=5. Linear-domain A' = 2^-eR * sum_j E_j*A[pred_j],
// E = exp2(K*m) fp16, precomputed by co-XCD producer blocks into a W=64-slot
// ring in d_ws (20 MB, L2/L3-resident). R12 proved producers land on the
// consumer's XCD (bid%8) and E reads L2-hit; its 1480us came from fencing
// storms (per-chunk 16-wave acquires + per-chunk wbl2 releases). R13:
//  - producer verifies co-XCD via s_getreg(XCC_ID) exchange: same XCD ->
//    RELAXED flag stores (shared L2 makes data visible; __syncthreads already
//    drained stores); cross-XCD (heuristic failed) -> per-chunk RELEASE.
//  - consumer: acquire-inv at startup + ring-WRAP only (every 64 steps,
//    single lane+barriers). Dirty fast-path E survives inv (R12 empirical).
//  - consumer hot loop: 3 coalesced plane loads (dword/dword/ushort,
//    lane-stride 4B - kills the scattered-20B L1 slow path of R9), 5 fp16
//    unpack + 5 fma + 4 dpp, deadbeat pow2 renorm, zero transcendentals,
//    8-deep register pipeline, one barrier/step.
// All blocks LDS-padded -> 1 block/CU. Fallback = exact R9 (640 us).

#define NB 32
#define SD 1024
#define CD 5120
#define WR 64
#define WMASK 63
#define DONE_S 0x7fffffff
#define AHEAD 24
#define CHUNK 8

typedef float f4a __attribute__((ext_vector_type(4), aligned(4)));
typedef _Float16 h2v __attribute__((ext_vector_type(2)));
typedef unsigned int u32;
typedef unsigned short u16;

__device__ __forceinline__ float fexp2(float x) { return __builtin_amdgcn_exp2f(x); }
__device__ __forceinline__ float flog2(float x) { return __builtin_amdgcn_logf(x); }
__device__ __forceinline__ u32 pkh(float a, float b) {
  return __builtin_bit_cast(u32, __builtin_amdgcn_cvt_pkrtz(a, b));
}
__device__ __forceinline__ u16 f2h(float f) { _Float16 h = (_Float16)f; return __builtin_bit_cast(u16, h); }
__device__ __forceinline__ float h2f(u16 b) { return (float)__builtin_bit_cast(_Float16, b); }

template <int CTRL>
__device__ __forceinline__ float dppq(float v) {
  return __int_as_float(
      __builtin_amdgcn_update_dpp(0, __float_as_int(v), CTRL, 0xF, 0xF, true));
}

// ws ints: [0..2047] prog block (n*64: +0 progress, +32 xcc). [2048..6143]
// flags (n*128+c). byte 65536+: EA u32[32][64][1024], EB same, EC u16[32][64][1024].
__global__ void init_ws(int* ws) {
  const int i = threadIdx.x;
#pragma unroll
  for (int k = 0; k < 6; ++k) ws[i + (k << 10)] = 0;
  // kernel-end implicit flush publishes these zeros device-wide.
}

__global__ void __launch_bounds__(1024) ctc_fused(const float* __restrict__ scores,
                                                  float* __restrict__ out,
                                                  int* __restrict__ ws, int T) {
  __shared__ float ap[2 * SD];
  __shared__ float red[16];
  __shared__ float pad[19456];   // >80KB total LDS -> 1 block/CU
  __shared__ int pmsg;

  const int bid = blockIdx.x;
  const int u = threadIdx.x;
  if (T < 0) { pad[u] = 1.f; out[0] = pad[u ^ 1]; }

  int* prog = ws;
  int* flags = ws + 2048;
  u32* EA = (u32*)((char*)ws + 65536);
  u32* EB = EA + (size_t)32 * WR * 1024;
  u16* EC = (u16*)(EB + (size_t)32 * WR * 1024);
  const size_t tstr = (size_t)NB * CD;
  const int NC = (T + 15) >> 4;

  int myx;
  asm volatile("s_getreg_b32 %0, hwreg(20, 0, 32)" : "=s"(myx));  // XCC_ID
  myx &= 15;

  if (bid >= NB) {
    // ------------------------------ producer ------------------------------
    const int h = bid - NB;
    const int n = h & 31;                // same XCD as consumer n (mod 8)
    const int k = h >> 5;                // 0..5
    u32* EAw = EA + (size_t)n * WR * 1024;
    u32* EBw = EB + (size_t)n * WR * 1024;
    u16* ECw = EC + (size_t)n * WR * 1024;
    const float K = 1.44269504088896340736f;

    // learn consumer's XCC -> pick flag-store mode
    int ccx;
    for (;;) {
      if (u == 0)
        pmsg = __hip_atomic_load(&prog[(n << 6) + 32], __ATOMIC_RELAXED, __HIP_MEMORY_SCOPE_AGENT);
      __syncthreads();
      ccx = pmsg;
      __syncthreads();
      if (ccx) break;
      __builtin_amdgcn_s_sleep(8);
    }
    const bool fast = ((ccx - 1) == myx);

    for (int c = k; (c << 4) < T; c += 6) {
      const int t0 = c << 4;
      for (;;) {
        if (u == 0) {
          int p = __hip_atomic_load(&prog[n << 6], __ATOMIC_RELAXED, __HIP_MEMORY_SCOPE_AGENT);
          pmsg = (p == DONE_S) ? 2 : ((t0 + 15 < p + WR) ? 1 : 0);
        }
        __syncthreads();
        const int st = pmsg;
        __syncthreads();
        if (st == 2) return;
        if (st == 1) break;
        __builtin_amdgcn_s_sleep(16);
      }
      const float* sp = scores + (size_t)n * CD + (size_t)t0 * tstr + (size_t)u * 5;
      const int lim = (T - t0 < 16) ? (T - t0) : 16;
#define PEMIT(RA, RB, S)                                                     \
  {                                                                          \
    const int slot = (t0 + (S)) & WMASK;                                     \
    EAw[(slot << 10) + u] = pkh(fexp2(RA.x * K), fexp2(RA.y * K));           \
    EBw[(slot << 10) + u] = pkh(fexp2(RA.z * K), fexp2(RA.w * K));           \
    ECw[(slot << 10) + u] = f2h(fexp2(RB * K));                              \
  }
      f4a ra0, ra1; float rb0, rb1;
      ra0 = __builtin_nontemporal_load((const f4a*)sp);
      rb0 = __builtin_nontemporal_load(sp + 4);
      sp += tstr;
      if (lim > 1) {
        ra1 = __builtin_nontemporal_load((const f4a*)sp);
        rb1 = __builtin_nontemporal_load(sp + 4);
      }
      sp += tstr;
      int s = 0;
      for (;;) {
        PEMIT(ra0, rb0, s);
        if (s + 2 < lim) {
          ra0 = __builtin_nontemporal_load((const f4a*)sp);
          rb0 = __builtin_nontemporal_load(sp + 4);
          sp += tstr;
        }
        if (++s >= lim) break;
        PEMIT(ra1, rb1, s);
        if (s + 2 < lim) {
          ra1 = __builtin_nontemporal_load((const f4a*)sp);
          rb1 = __builtin_nontemporal_load(sp + 4);
          sp += tstr;
        }
        if (++s >= lim) break;
      }
#undef PEMIT
      __syncthreads();  // vmcnt(0) per wave: all E stores L2-ack'd
      if (u == 0) {
        if (fast)   // shared L2 holds the data; no wbl2 needed
          __hip_atomic_store(&flags[(n << 7) + c], 1, __ATOMIC_RELEASE ? __ATOMIC_RELAXED : __ATOMIC_RELAXED, __HIP_MEMORY_SCOPE_AGENT);
        else        // cross-XCD: full release (wbl2) publishes data to MALL
          __hip_atomic_store(&flags[(n << 7) + c], 1, __ATOMIC_RELEASE, __HIP_MEMORY_SCOPE_AGENT);
      }
    }
    return;
  }

  // ------------------------------- consumer -------------------------------
  {
    const int n = bid;
    const int lane = u & 63;
    const int wid = u >> 6;
    const int p = u >> 2, c = u & 3;
    const int rdoff = (c << 8) | (p ^ (c << 3));
    const int wroff = u ^ ((u & 0x300) >> 5);

    ap[u] = 1.f; ap[SD + u] = 1.f;
    float a_cur = 1.f;
    int cacc = 0;
    const float LN2 = 0.69314718055994530942f;

    if (u == 0)   // publish my XCC (nonzero-coded) for producers
      __hip_atomic_store(&prog[(n << 6) + 32], myx + 1, __ATOMIC_RELAXED, __HIP_MEMORY_SCOPE_AGENT);

    const u32* EAr = EA + (size_t)n * WR * 1024;
    const u32* EBr = EB + (size_t)n * WR * 1024;
    const u16* ECr = EC + (size_t)n * WR * 1024;

    auto wait_flag = [&](int cidx, bool acq) {
      for (;;) {
        if (u == 0)
          pmsg = __hip_atomic_load(&flags[(n << 7) + cidx], __ATOMIC_RELAXED, __HIP_MEMORY_SCOPE_AGENT);
        asm volatile("s_waitcnt lgkmcnt(0)\n\ts_barrier" ::: "memory");
        const int f = pmsg;
        asm volatile("s_barrier" ::: "memory");
        if (f) break;
        __builtin_amdgcn_s_sleep(2);
      }
      if (acq) {   // single-lane acquire: inv stale L1/L2 (wrap / cross-launch)
        if (u == 0)
          (void)__hip_atomic_load(&flags[(n << 7) + cidx], __ATOMIC_ACQUIRE, __HIP_MEMORY_SCOPE_AGENT);
        asm volatile("s_barrier" ::: "memory");
      }
    };

    auto LD1 = [&](int tt, u32& qa, u32& qb, u16& qc) {
      const int tc = tt < T ? tt : T - 1;
      const int slot = tc & WMASK;
      qa = EAr[(slot << 10) + u];   // lane-stride-4B coalesced dword
      qb = EBr[(slot << 10) + u];
      qc = ECr[(slot << 10) + u];
    };

    auto CP = [&](int t, u32 qa, u32 qb, u16 qc) {
      const int rb = ((t + 1) & 1) << 10;
      const float vr = ap[rb + rdoff];
      const float R = ap[rb];
      const float p0 = dppq<0x00>(vr);
      const float p1 = dppq<0x55>(vr);
      const float p2 = dppq<0xAA>(vr);
      const float p3 = dppq<0xFF>(vr);
      float s = h2f((u16)(qa & 0xffff)) * a_cur;
      s = __builtin_fmaf(h2f((u16)(qa >> 16)), p0, s);
      s = __builtin_fmaf(h2f((u16)(qb & 0xffff)), p1, s);
      s = __builtin_fmaf(h2f((u16)(qb >> 16)), p2, s);
      s = __builtin_fmaf(h2f(qc), p3, s);
      const int eR = (__float_as_int(R) >> 23) & 0xFF;   // deadbeat renorm
      cacc += eR - 127;
      s *= __int_as_float((254 - eR) << 23);
      a_cur = s;
      ap[((t & 1) << 10) + wroff] = s;
      if (((t & 3) == 0) && (u == 0))
        __hip_atomic_store(&prog[n << 6], t, __ATOMIC_RELAXED, __HIP_MEMORY_SCOPE_AGENT);
      asm volatile("s_waitcnt lgkmcnt(0)\n\ts_barrier" ::: "memory");
    };

    u32 qa0, qa1, qa2, qa3, qa4, qa5, qa6, qa7;
    u32 qb0, qb1, qb2, qb3, qb4, qb5, qb6, qb7;
    u16 qc0, qc1, qc2, qc3, qc4, qc5, qc6, qc7;
    wait_flag(0, true);                    // startup acquire (cross-launch)
    LD1(0, qa0, qb0, qc0); LD1(1, qa1, qb1, qc1);
    LD1(2, qa2, qb2, qc2); LD1(3, qa3, qb3, qc3);
    LD1(4, qa4, qb4, qc4); LD1(5, qa5, qb5, qc5);
    LD1(6, qa6, qb6, qc6); LD1(7, qa7, qb7, qc7);
    asm volatile("s_waitcnt lgkmcnt(0)\n\ts_barrier" ::: "memory");  // ap init

    int t = 0;
    for (int cb = 0; cb < NC; ++cb) {
      if (cb + 1 < NC) {
        const bool wrap = (((cb + 1) & 3) == 0);  // new 64-step generation
        wait_flag(cb + 1, wrap);
      }
#define STEP(SS) if (t < T) { CP(t, qa##SS, qb##SS, qc##SS); LD1(t + 8, qa##SS, qb##SS, qc##SS); ++t; }
      STEP(0) STEP(1) STEP(2) STEP(3) STEP(4) STEP(5) STEP(6) STEP(7)
      STEP(0) STEP(1) STEP(2) STEP(3) STEP(4) STEP(5) STEP(6) STEP(7)
#undef STEP
    }

    if (u == 0)
      __hip_atomic_store(&prog[n << 6], DONE_S, __ATOMIC_RELAXED, __HIP_MEMORY_SCOPE_AGENT);

    float v = a_cur;
#pragma unroll
    for (int d = 1; d < 64; d <<= 1) v += __shfl_xor(v, d, 64);
    if (lane == 0) red[wid] = v;
    __syncthreads();
    if (u == 0) {
      float ssum = red[0];
#pragma unroll
      for (int i = 1; i < 16; ++i) ssum += red[i];
      out[n] = LN2 * ((float)cacc + flog2(ssum));
    }
  }
}

// ------------------------------ fallback = exact R9 -------------------------
__global__ void __launch_bounds__(1024) ctc_base(const float* __restrict__ scores,
                                                 float* __restrict__ out,
                                                 int* __restrict__ prog, int T) {
  __shared__ float ap[2 * SD];
  __shared__ float red[16];
  __shared__ float pad[19456];
  __shared__ int pmsg;

  const int bid = blockIdx.x;
  const int u = threadIdx.x;
  if (T < 0) { pad[u] = 1.f; out[0] = pad[u ^ 1]; }
  const size_t tstr = (size_t)NB * CD;

  if (bid >= NB) {
    const int h = bid - NB;
    const int n = h & 31;
    const int parity = h >> 5;
    const float* base = scores + (size_t)n * CD;
    float acc = 0.f;
    for (int c = parity; c * CHUNK < T; c += 2) {
      const int t0 = c * CHUNK;
      int p;
      for (;;) {
        if (u == 0)
          pmsg = __hip_atomic_load(&prog[n * 64], __ATOMIC_RELAXED, __HIP_MEMORY_SCOPE_AGENT);
        __syncthreads();
        p = pmsg;
        __syncthreads();
        if (p == DONE_S || t0 < p + AHEAD) break;
        __builtin_amdgcn_s_sleep(8);
      }
      if (p == DONE_S) break;
      if (t0 + CHUNK <= p) continue;
      if (u < 320) {
        const float* cb = base + (size_t)t0 * tstr + (size_t)u * 16;
        const int lim = (T - t0 < CHUNK) ? (T - t0) : CHUNK;
        for (int s = 0; s < lim; ++s) { acc += *cb; cb += tstr; }
      }
    }
    asm volatile("" ::"v"(acc));
    return;
  }

  const int n = bid;
  const int lane = u & 63;
  const int wid = u >> 6;
  const int p = u >> 2, c = u & 3;
  const int rdoff = (c << 8) | (p ^ (c << 3));
  const int wroff = u ^ ((u & 0x300) >> 5);

  ap[u] = 1.f; ap[SD + u] = 1.f;
  float a_cur = 1.f;
  float nLf = 0.f;
  int Lnext = 0, cacc = 0;
  const float K = 1.44269504088896340736f;
  const float LN2 = 0.69314718055994530942f;
  const float* sn = scores + (size_t)n * CD + (size_t)u * 5;
  const size_t str4 = 4 * tstr;

  auto CP = [&](int t, const f4a& qa, float qb) {
    const int rb = ((t + 1) & 1) * SD;
    const float vr = ap[rb + rdoff];
    const float R = ap[rb];
    const float p0 = dppq<0x00>(vr);
    const float p1 = dppq<0x55>(vr);
    const float p2 = dppq<0xAA>(vr);
    const float p3 = dppq<0xFF>(vr);
    float e0 = fexp2(__builtin_fmaf(qa.x, K, nLf));
    float e1 = fexp2(__builtin_fmaf(qa.y, K, nLf));
    float e2 = fexp2(__builtin_fmaf(qa.z, K, nLf));
    float e3 = fexp2(__builtin_fmaf(qa.w, K, nLf));
    float e4 = fexp2(__builtin_fmaf(qb,   K, nLf));
    float s = e0 * a_cur;
    s = __builtin_fmaf(e1, p0, s);
    s = __builtin_fmaf(e2, p1, s);
    s = __builtin_fmaf(e3, p2, s);
    s = __builtin_fmaf(e4, p3, s);
    a_cur = s;
    cacc += Lnext;
    ap[(t & 1) * SD + wroff] = s;
    const int xb = ((__float_as_int(R) >> 23) & 0xFF) - 127;
    Lnext = xb >> 2;
    nLf = (float)(-Lnext);
    if (((t & 3) == 0) && (u == 0))
      __hip_atomic_store(&prog[n * 64], t, __ATOMIC_RELAXED, __HIP_MEMORY_SCOPE_AGENT);
    asm volatile("s_waitcnt lgkmcnt(0)\n\ts_barrier" ::: "memory");
  };

#define PRO(cc)                                                             \
  const float* P##cc = sn + (size_t)((cc) < T ? (cc) : T - 1) * tstr;       \
  f4a qa##cc = *(const f4a*)P##cc;                                          \
  float qb##cc = P##cc[4];                                                  \
  P##cc += str4;
  PRO(0) PRO(1) PRO(2) PRO(3)
#undef PRO
  __syncthreads();
#define RL(cc)                                                              \
  qa##cc = *(const f4a*)P##cc;                                              \
  qb##cc = P##cc[4];                                                        \
  P##cc += str4;
  int t = 0;
  for (; t + 8 <= T; t += 4) {
    CP(t + 0, qa0, qb0); RL(0)
    CP(t + 1, qa1, qb1); RL(1)
    CP(t + 2, qa2, qb2); RL(2)
    CP(t + 3, qa3, qb3); RL(3)
  }
#undef RL
#define EPI1(cc)                                                            \
  if (t + (cc) < T) {                                                       \
    CP(t + (cc), qa##cc, qb##cc);                                           \
    if (t + 4 + (cc) < T) { qa##cc = *(const f4a*)P##cc; qb##cc = P##cc[4]; }\
  }
  EPI1(0) EPI1(1) EPI1(2) EPI1(3)
#undef EPI1
  t += 4;
#define EPI2(cc) if (t + (cc) < T) CP(t + (cc), qa##cc, qb##cc);
  EPI2(0) EPI2(1) EPI2(2) EPI2(3)
#undef EPI2

  if (u == 0)
    __hip_atomic_store(&prog[n * 64], DONE_S, __ATOMIC_RELAXED, __HIP_MEMORY_SCOPE_AGENT);

  float v = a_cur;
#pragma unroll
  for (int d = 1; d < 64; d <<= 1) v += __shfl_xor(v, d, 64);
  if (lane == 0) red[wid] = v;
  __syncthreads();
  if (u == 0) {
    float ssum = red[0];
#pragma unroll
    for (int i = 1; i < 16; ++i) ssum += red[i];
    out[n] = LN2 * ((float)cacc + flog2(ssum));
  }
}

extern "C" void kernel_launch(void* const* d_in, const int* in_sizes, int n_in,
                              void* d_out, int out_size, void* d_ws, size_t ws_size,
                              hipStream_t stream) {
  const float* scores = (const float*)d_in[0];
  float* out = (float*)d_out;
  int* ws = (int*)d_ws;
  const long long tot = (long long)in_sizes[0];
  const int T = (int)(tot / ((long long)NB * CD));

  const size_t need = 65536 + (size_t)32 * WR * 10240;  // ~21 MB (R12-proven)
  init_ws<<<dim3(1), dim3(1024), 0, stream>>>(ws);
  if (ws_size >= need && T <= 2048 && T >= 16) {
    ctc_fused<<<dim3(224), dim3(1024), 0, stream>>>(scores, out, ws, T);
  } else {
    ctc_base<<<dim3(96), dim3(1024), 0, stream>>>(scores, out, ws, T);
  }
}

// Round 14
// 1016.042 us; speedup vs baseline: 1.4569x; 1.0650x over previous
//
#include <hip/hip_runtime.h>
#include <cstdint>
#include <cstddef>

// CTC-CRF logZ: S=1024, NZ=5. Consumer recursion reads PRECOMPUTED fp16
// U = exp2(K*m): 10 KB/step = 160 cache lines/step (vs 320 for fp32 scores).
// R9's 768 cyc/step == 320 lines x ~150cyc / ~64 outstanding -> lines are
// the per-CU wall; halving lines is the lever. R11/12/13 failed because
// store-heavy producers shared the consumer's XCD (L2 churn + ring invs).
// R14: (a) FULL E array in d_ws (no ring -> no generations -> no acquires);
// (b) consumers on XCDs 0-3 with READ-ONLY warmers (3/batch, R9-proven);
// (c) producers (4/batch) on XCDs 4-7 (bid%8 = n%4+4): their stores/wbl2
// churn foreign L2s only; per-chunk RELEASE publishes E to MALL; warmers
// pull MALL->consumer-L2 inside a 32-step window. Per-chunk flags, agent
// atomics (R9-proven cross-XCD). Deterministic: flags re-zeroed per launch,
// consumer never reads unflagged chunks. Fallback = exact R9 (640us) when
// ws_size < ~656 MB.

#define NB 32
#define SD 1024
#define CD 5120
#define DONE_S 0x7fffffff
#define NWARM 32
#define AHEAD 24
#define CHUNK 8

typedef float f4a __attribute__((ext_vector_type(4), aligned(4)));
typedef unsigned int u32;
typedef unsigned short u16;

__device__ __forceinline__ float fexp2(float x) { return __builtin_amdgcn_exp2f(x); }
__device__ __forceinline__ float flog2(float x) { return __builtin_amdgcn_logf(x); }
__device__ __forceinline__ u32 pkh(float a, float b) {
  return __builtin_bit_cast(u32, __builtin_amdgcn_cvt_pkrtz(a, b));
}
__device__ __forceinline__ u16 f2h(float f) { _Float16 h = (_Float16)f; return __builtin_bit_cast(u16, h); }
__device__ __forceinline__ float h2f(u16 b) { return (float)__builtin_bit_cast(_Float16, b); }

template <int CTRL>
__device__ __forceinline__ float dppq(float v) {
  return __int_as_float(
      __builtin_amdgcn_update_dpp(0, __float_as_int(v), CTRL, 0xF, 0xF, true));
}

// ws ints: [0..2047] prog (n*64), [2048..6143] flags (n*128+c).
// byte 65536+: EA u32[32][T][1024], EB u32[32][T][1024], EC u16[32][T][1024].
__global__ void init_ws(int* ws) {
  const int i = threadIdx.x;
#pragma unroll
  for (int k = 0; k < 6; ++k) ws[i + (k << 10)] = 0;
}

__global__ void __launch_bounds__(1024) ctc_fused(const float* __restrict__ scores,
                                                  float* __restrict__ out,
                                                  int* __restrict__ ws, int T) {
  __shared__ float ap[2 * SD];
  __shared__ float red[16];
  __shared__ float pad[19456];   // >80KB total LDS -> 1 block/CU
  __shared__ int pmsg;

  const int bid = blockIdx.x;
  const int u = threadIdx.x;
  if (T < 0) { pad[u] = 1.f; out[0] = pad[u ^ 1]; }

  int* prog = ws;
  int* flags = ws + 2048;
  u32* EA = (u32*)((char*)ws + 65536);
  u32* EB = EA + (size_t)32 * T * 1024;
  u16* EC = (u16*)(EB + (size_t)32 * T * 1024);
  const size_t tstr = (size_t)NB * CD;
  const int NC = (T + 15) >> 4;

  const int x = bid & 7;
  const int r = bid >> 3;

  if (x >= 4) {
    // --------------- producer (XCDs 4-7; foreign to consumer) -------------
    const int n = (x - 4) + ((r & 7) << 2);  // n%4 = x-4 -> consumer on XCD x-4
    const int k = r >> 3;                    // 0..3, chunk stride 4
    u32* EAw = EA + (size_t)n * T * 1024;
    u32* EBw = EB + (size_t)n * T * 1024;
    u16* ECw = EC + (size_t)n * T * 1024;
    const float K = 1.44269504088896340736f;
    for (int c = k; c < NC; c += 4) {
      const int t0 = c << 4;
      const float* sp = scores + (size_t)n * CD + (size_t)t0 * tstr + (size_t)u * 5;
      const int lim = (T - t0 < 16) ? (T - t0) : 16;
#define PEMIT(RA, RB, S)                                                     \
  {                                                                          \
    const size_t ti = (size_t)(t0 + (S)) << 10;                              \
    EAw[ti + u] = pkh(fexp2(RA.x * K), fexp2(RA.y * K));                     \
    EBw[ti + u] = pkh(fexp2(RA.z * K), fexp2(RA.w * K));                     \
    ECw[ti + u] = f2h(fexp2(RB * K));                                        \
  }
      f4a ra0, ra1; float rb0, rb1;
      ra0 = *(const f4a*)sp; rb0 = sp[4]; sp += tstr;
      if (lim > 1) { ra1 = *(const f4a*)sp; rb1 = sp[4]; }
      sp += tstr;
      int s = 0;
      for (;;) {
        PEMIT(ra0, rb0, s);
        if (s + 2 < lim) { ra0 = *(const f4a*)sp; rb0 = sp[4]; sp += tstr; }
        if (++s >= lim) break;
        PEMIT(ra1, rb1, s);
        if (s + 2 < lim) { ra1 = *(const f4a*)sp; rb1 = sp[4]; sp += tstr; }
        if (++s >= lim) break;
      }
#undef PEMIT
      __syncthreads();  // vmcnt(0): all waves' E stores in L2
      if (u == 0)       // RELEASE: wbl2 on PRODUCER XCD -> E reaches MALL
        __hip_atomic_store(&flags[(n << 7) + c], 1, __ATOMIC_RELEASE, __HIP_MEMORY_SCOPE_AGENT);
    }
    return;
  }

  if (r >= 8) {
    // ------------- warmer (read-only, co-XCD with its consumer) -----------
    const int rr = r - 8;
    const int j = rr >> 3;                   // 0..2, chunk stride 3
    const int n = x + ((rr & 7) << 2);       // n%4 = x ✓
    const u32* EAc = EA + (size_t)n * T * 1024;
    const u32* EBc = EB + (size_t)n * T * 1024;
    const u16* ECc = EC + (size_t)n * T * 1024;
    int acc = 0;
    for (int cb = j; cb < NC; cb += 3) {
      for (;;) {
        if (u == 0) {
          int f = __hip_atomic_load(&flags[(n << 7) + cb], __ATOMIC_RELAXED, __HIP_MEMORY_SCOPE_AGENT);
          int p = __hip_atomic_load(&prog[n << 6], __ATOMIC_RELAXED, __HIP_MEMORY_SCOPE_AGENT);
          pmsg = (p == DONE_S) ? 2 : ((f && ((cb << 4) < p + NWARM)) ? 1 : 0);
        }
        __syncthreads();
        const int st = pmsg;
        __syncthreads();
        if (st == 2) goto wdone;
        if (st == 1) break;
        __builtin_amdgcn_s_sleep(8);
      }
      {
        const size_t t0 = (size_t)(cb << 4) << 10;
        acc += (int)EAc[t0 + (u << 4)];              // 1024 lines, 1 dword each
        acc += (int)EBc[t0 + (u << 4)];
        if (u < 512) acc += (int)ECc[t0 + (u << 5)]; // 512 lines
      }
    }
  wdone:
    asm volatile("" ::"v"(acc));
    return;
  }

  // ---------------- consumer (XCDs 0-3, store-free L2) --------------------
  {
    const int n = x + (r << 2);              // n%4 = x ✓
    const int lane = u & 63;
    const int wid = u >> 6;
    const int p = u >> 2, c = u & 3;
    const int rdoff = (c << 8) | (p ^ (c << 3));   // conflict-free swizzle
    const int wroff = u ^ ((u & 0x300) >> 5);

    ap[u] = 1.f; ap[SD + u] = 1.f;
    float a_cur = 1.f;
    int cacc = 0;
    const float LN2 = 0.69314718055994530942f;

    const u32* EAc = EA + (size_t)n * T * 1024;
    const u32* EBc = EB + (size_t)n * T * 1024;
    const u16* ECc = EC + (size_t)n * T * 1024;

    auto wait_flag = [&](int cidx) {   // relaxed only: no invalidation ever
      for (;;) {
        if (u == 0)
          pmsg = __hip_atomic_load(&flags[(n << 7) + cidx], __ATOMIC_RELAXED, __HIP_MEMORY_SCOPE_AGENT);
        asm volatile("s_waitcnt lgkmcnt(0)\n\ts_barrier" ::: "memory");
        const int f = pmsg;
        asm volatile("s_barrier" ::: "memory");
        if (f) break;
        __builtin_amdgcn_s_sleep(2);
      }
    };

    auto LD1 = [&](int tt, u32& qa, u32& qb, u16& qc) {
      const int tc = tt < T ? tt : T - 1;
      const unsigned o = ((unsigned)tc << 10) + (unsigned)u;
      qa = EAc[o];   // coalesced dword planes
      qb = EBc[o];
      qc = ECc[o];
    };

    auto CP = [&](int t, u32 qa, u32 qb, u16 qc) {
      const int rb = ((t + 1) & 1) << 10;
      const float vr = ap[rb + rdoff];    // pred read, conflict-free
      const float R = ap[rb];             // uniform -> broadcast
      const float p0 = dppq<0x00>(vr);
      const float p1 = dppq<0x55>(vr);
      const float p2 = dppq<0xAA>(vr);
      const float p3 = dppq<0xFF>(vr);
      float s = h2f((u16)(qa & 0xffff)) * a_cur;
      s = __builtin_fmaf(h2f((u16)(qa >> 16)), p0, s);
      s = __builtin_fmaf(h2f((u16)(qb & 0xffff)), p1, s);
      s = __builtin_fmaf(h2f((u16)(qb >> 16)), p2, s);
      s = __builtin_fmaf(h2f(qc), p3, s);
      const int eR = (__float_as_int(R) >> 23) & 0xFF;   // deadbeat renorm
      cacc += eR - 127;
      s *= __int_as_float((254 - eR) << 23);
      a_cur = s;
      ap[((t & 1) << 10) + wroff] = s;
      if (((t & 3) == 0) && (u == 0))
        __hip_atomic_store(&prog[n << 6], t, __ATOMIC_RELAXED, __HIP_MEMORY_SCOPE_AGENT);
      asm volatile("s_waitcnt lgkmcnt(0)\n\ts_barrier" ::: "memory");
    };

    u32 qa0, qa1, qa2, qa3, qa4, qa5, qa6, qa7;
    u32 qb0, qb1, qb2, qb3, qb4, qb5, qb6, qb7;
    u16 qc0, qc1, qc2, qc3, qc4, qc5, qc6, qc7;
    wait_flag(0);
    LD1(0, qa0, qb0, qc0); LD1(1, qa1, qb1, qc1);
    LD1(2, qa2, qb2, qc2); LD1(3, qa3, qb3, qc3);
    LD1(4, qa4, qb4, qc4); LD1(5, qa5, qb5, qc5);
    LD1(6, qa6, qb6, qc6); LD1(7, qa7, qb7, qc7);
    asm volatile("s_waitcnt lgkmcnt(0)\n\ts_barrier" ::: "memory");  // ap init

    int t = 0;
    for (int cb = 0; cb < NC; ++cb) {
      if (cb + 1 < NC) wait_flag(cb + 1);   // covers prefetch into cb+1
#define STEP(SS) if (t < T) { CP(t, qa##SS, qb##SS, qc##SS); LD1(t + 8, qa##SS, qb##SS, qc##SS); ++t; }
      STEP(0) STEP(1) STEP(2) STEP(3) STEP(4) STEP(5) STEP(6) STEP(7)
      STEP(0) STEP(1) STEP(2) STEP(3) STEP(4) STEP(5) STEP(6) STEP(7)
#undef STEP
    }

    if (u == 0)
      __hip_atomic_store(&prog[n << 6], DONE_S, __ATOMIC_RELAXED, __HIP_MEMORY_SCOPE_AGENT);

    float v = a_cur;
#pragma unroll
    for (int d = 1; d < 64; d <<= 1) v += __shfl_xor(v, d, 64);
    if (lane == 0) red[wid] = v;
    __syncthreads();
    if (u == 0) {
      float ssum = red[0];
#pragma unroll
      for (int i = 1; i < 16; ++i) ssum += red[i];
      out[n] = LN2 * ((float)cacc + flog2(ssum));
    }
  }
}

// ------------------------------ fallback = exact R9 -------------------------
__global__ void __launch_bounds__(1024) ctc_base(const float* __restrict__ scores,
                                                 float* __restrict__ out,
                                                 int* __restrict__ prog, int T) {
  __shared__ float ap[2 * SD];
  __shared__ float red[16];
  __shared__ float pad[19456];
  __shared__ int pmsg;

  const int bid = blockIdx.x;
  const int u = threadIdx.x;
  if (T < 0) { pad[u] = 1.f; out[0] = pad[u ^ 1]; }
  const size_t tstr = (size_t)NB * CD;

  if (bid >= NB) {
    const int h = bid - NB;
    const int n = h & 31;
    const int parity = h >> 5;
    const float* base = scores + (size_t)n * CD;
    float acc = 0.f;
    for (int c = parity; c * CHUNK < T; c += 2) {
      const int t0 = c * CHUNK;
      int p;
      for (;;) {
        if (u == 0)
          pmsg = __hip_atomic_load(&prog[n * 64], __ATOMIC_RELAXED, __HIP_MEMORY_SCOPE_AGENT);
        __syncthreads();
        p = pmsg;
        __syncthreads();
        if (p == DONE_S || t0 < p + AHEAD) break;
        __builtin_amdgcn_s_sleep(8);
      }
      if (p == DONE_S) break;
      if (t0 + CHUNK <= p) continue;
      if (u < 320) {
        const float* cb = base + (size_t)t0 * tstr + (size_t)u * 16;
        const int lim = (T - t0 < CHUNK) ? (T - t0) : CHUNK;
        for (int s = 0; s < lim; ++s) { acc += *cb; cb += tstr; }
      }
    }
    asm volatile("" ::"v"(acc));
    return;
  }

  const int n = bid;
  const int lane = u & 63;
  const int wid = u >> 6;
  const int p = u >> 2, c = u & 3;
  const int rdoff = (c << 8) | (p ^ (c << 3));
  const int wroff = u ^ ((u & 0x300) >> 5);

  ap[u] = 1.f; ap[SD + u] = 1.f;
  float a_cur = 1.f;
  float nLf = 0.f;
  int Lnext = 0, cacc = 0;
  const float K = 1.44269504088896340736f;
  const float LN2 = 0.69314718055994530942f;
  const float* sn = scores + (size_t)n * CD + (size_t)u * 5;
  const size_t str4 = 4 * tstr;

  auto CP = [&](int t, const f4a& qa, float qb) {
    const int rb = ((t + 1) & 1) * SD;
    const float vr = ap[rb + rdoff];
    const float R = ap[rb];
    const float p0 = dppq<0x00>(vr);
    const float p1 = dppq<0x55>(vr);
    const float p2 = dppq<0xAA>(vr);
    const float p3 = dppq<0xFF>(vr);
    float e0 = fexp2(__builtin_fmaf(qa.x, K, nLf));
    float e1 = fexp2(__builtin_fmaf(qa.y, K, nLf));
    float e2 = fexp2(__builtin_fmaf(qa.z, K, nLf));
    float e3 = fexp2(__builtin_fmaf(qa.w, K, nLf));
    float e4 = fexp2(__builtin_fmaf(qb,   K, nLf));
    float s = e0 * a_cur;
    s = __builtin_fmaf(e1, p0, s);
    s = __builtin_fmaf(e2, p1, s);
    s = __builtin_fmaf(e3, p2, s);
    s = __builtin_fmaf(e4, p3, s);
    a_cur = s;
    cacc += Lnext;
    ap[(t & 1) * SD + wroff] = s;
    const int xb = ((__float_as_int(R) >> 23) & 0xFF) - 127;
    Lnext = xb >> 2;
    nLf = (float)(-Lnext);
    if (((t & 3) == 0) && (u == 0))
      __hip_atomic_store(&prog[n * 64], t, __ATOMIC_RELAXED, __HIP_MEMORY_SCOPE_AGENT);
    asm volatile("s_waitcnt lgkmcnt(0)\n\ts_barrier" ::: "memory");
  };

#define PRO(cc)                                                             \
  const float* P##cc = sn + (size_t)((cc) < T ? (cc) : T - 1) * tstr;       \
  f4a qa##cc = *(const f4a*)P##cc;                                          \
  float qb##cc = P##cc[4];                                                  \
  P##cc += str4;
  PRO(0) PRO(1) PRO(2) PRO(3)
#undef PRO
  __syncthreads();
#define RL(cc)                                                              \
  qa##cc = *(const f4a*)P##cc;                                              \
  qb##cc = P##cc[4];                                                        \
  P##cc += str4;
  int t = 0;
  for (; t + 8 <= T; t += 4) {
    CP(t + 0, qa0, qb0); RL(0)
    CP(t + 1, qa1, qb1); RL(1)
    CP(t + 2, qa2, qb2); RL(2)
    CP(t + 3, qa3, qb3); RL(3)
  }
#undef RL
#define EPI1(cc)                                                            \
  if (t + (cc) < T) {                                                       \
    CP(t + (cc), qa##cc, qb##cc);                                           \
    if (t + 4 + (cc) < T) { qa##cc = *(const f4a*)P##cc; qb##cc = P##cc[4]; }\
  }
  EPI1(0) EPI1(1) EPI1(2) EPI1(3)
#undef EPI1
  t += 4;
#define EPI2(cc) if (t + (cc) < T) CP(t + (cc), qa##cc, qb##cc);
  EPI2(0) EPI2(1) EPI2(2) EPI2(3)
#undef EPI2

  if (u == 0)
    __hip_atomic_store(&prog[n * 64], DONE_S, __ATOMIC_RELAXED, __HIP_MEMORY_SCOPE_AGENT);

  float v = a_cur;
#pragma unroll
  for (int d = 1; d < 64; d <<= 1) v += __shfl_xor(v, d, 64);
  if (lane == 0) red[wid] = v;
  __syncthreads();
  if (u == 0) {
    float ssum = red[0];
#pragma unroll
    for (int i = 1; i < 16; ++i) ssum += red[i];
    out[n] = LN2 * ((float)cacc + flog2(ssum));
  }
}

extern "C" void kernel_launch(void* const* d_in, const int* in_sizes, int n_in,
                              void* d_out, int out_size, void* d_ws, size_t ws_size,
                              hipStream_t stream) {
  const float* scores = (const float*)d_in[0];
  float* out = (float*)d_out;
  int* ws = (int*)d_ws;
  const long long tot = (long long)in_sizes[0];
  const int T = (int)(tot / ((long long)NB * CD));

  const size_t need = 65536 + (size_t)32 * (size_t)T * 10240;  // full E array
  init_ws<<<dim3(1), dim3(1024), 0, stream>>>(ws);
  if (ws_size >= need && T >= 32 && T <= 2048) {
    ctc_fused<<<dim3(256), dim3(1024), 0, stream>>>(scores, out, ws, T);
  } else {
    ctc_base<<<dim3(96), dim3(1024), 0, stream>>>(scores, out, ws, T);
  }
}

// Round 15
// 636.896 us; speedup vs baseline: 2.3243x; 1.5953x over previous
//
#include <hip/hip_runtime.h>
#include <cstdint>
#include <cstddef>

// CTC-CRF logZ forward: S=1024, NZ=5, linear-domain, damped pow2 renorm.
// == R9 (640us, session best) with ONE change: 3 near-warmers/batch
// (3-way chunk striping) instead of 2. R10-R14 established:
//  - consumer floor = ~640 L1 line-touches/step (2 VMEM instr/thread x 16
//    waves x 20 lines) + ~400cyc VALU/trans + ~280cyc DS, lockstep-overlapped
//    -> 768 cyc/step; warming shaves the HBM-latency part (925->768).
//  - E-precompute (fp16, half the lines) loses on THIS hardware: cross-XCD
//    publish needs per-chunk wbl2 storms (R12/R14); same-XCD producers
//    poison the consumer L2 with their score streaming (R13). 4 attempts,
//    all >= 1016us vs 640us.
//  - redistribution schemes (quad-coop loads, plane loads + LDS, gll)
//    trade ~320 saved touches for >=480cyc DS - computed dead ends.
// Warmers are read-only co-XCD L2 prefetchers (R9-proven +16%).

#define NB 32
#define SD 1024
#define CD 5120
#define AHEAD 24
#define CHUNK 8
#define DONE_S 0x7fffffff

typedef float f4a __attribute__((ext_vector_type(4), aligned(4)));

__device__ __forceinline__ float fexp2(float x) { return __builtin_amdgcn_exp2f(x); }
__device__ __forceinline__ float flog2(float x) { return __builtin_amdgcn_logf(x); }

template <int CTRL>
__device__ __forceinline__ float dppq(float v) {
  return __int_as_float(
      __builtin_amdgcn_update_dpp(0, __float_as_int(v), CTRL, 0xF, 0xF, true));
}

__global__ void init_prog(int* prog) {
  const int i = threadIdx.x;
  if (i < NB) prog[i * 64] = 0;
}

__global__ void __launch_bounds__(1024) ctc_logz(const float* __restrict__ scores,
                                                 float* __restrict__ out,
                                                 int* __restrict__ prog, int T) {
  __shared__ float ap[2 * SD];
  __shared__ float red[16];
  __shared__ float pad[19456];   // 76KB pad -> 1 block/CU guaranteed
  __shared__ int pmsg;

  const int bid = blockIdx.x;
  const int u = threadIdx.x;
  if (T < 0) { pad[u] = 1.f; out[0] = pad[u ^ 1]; }  // keep pad allocated

  const size_t tstr = (size_t)NB * CD;

  if (bid >= NB) {
    // ---------- warmer: read-only L3->L2 prefetch on consumer's XCD --------
    const int h = bid - NB;
    const int n = h & 31;          // batch (same XCD as consumer n, mod 8)
    const int j = h >> 5;          // 0,1,2: 3-way chunk striping
    const float* base = scores + (size_t)n * CD;
    float acc = 0.f;
    for (int c = j; c * CHUNK < T; c += 3) {
      const int t0 = c * CHUNK;
      int p;
      for (;;) {
        if (u == 0)
          pmsg = __hip_atomic_load(&prog[n * 64], __ATOMIC_RELAXED, __HIP_MEMORY_SCOPE_AGENT);
        __syncthreads();
        p = pmsg;
        __syncthreads();
        if (p == DONE_S || t0 < p + AHEAD) break;
        __builtin_amdgcn_s_sleep(8);    // ~512 cyc
      }
      if (p == DONE_S) break;
      if (t0 + CHUNK <= p) continue;
      if (u < 320) {                    // 320 x 64B lines = one 20KB step
        const float* cb = base + (size_t)t0 * tstr + (size_t)u * 16;
        const int lim = (T - t0 < CHUNK) ? (T - t0) : CHUNK;
        for (int s = 0; s < lim; ++s) { acc += *cb; cb += tstr; }
      }
    }
    asm volatile("" ::"v"(acc));        // DCE sink
    return;
  }

  // ------------------------- consumer path (R7/R9) -----------------------
  const int n = bid;
  const int lane = u & 63;
  const int wid = u >> 6;
  const int p = u >> 2, c = u & 3;
  const int rdoff = (c << 8) | (p ^ (c << 3));   // slot(p + 256c), swizzled
  const int wroff = u ^ ((u & 0x300) >> 5);      // slot(u)

  ap[u] = 1.f; ap[SD + u] = 1.f;
  float a_cur = 1.f;
  float nLf = 0.f;
  int Lnext = 0, cacc = 0;

  const float K = 1.44269504088896340736f;
  const float LN2 = 0.69314718055994530942f;

  const float* sn = scores + (size_t)n * CD + (size_t)u * 5;
  const size_t str4 = 4 * tstr;

  auto CP = [&](int t, const f4a& qa, float qb) {
    const int rb = ((t + 1) & 1) * SD;
    const float vr = ap[rb + rdoff];    // pred read, conflict-free
    const float R = ap[rb];             // uniform addr -> broadcast
    const float p0 = dppq<0x00>(vr);    // A[p]
    const float p1 = dppq<0x55>(vr);    // A[256+p]
    const float p2 = dppq<0xAA>(vr);    // A[512+p]
    const float p3 = dppq<0xFF>(vr);    // A[768+p]
    float e0 = fexp2(__builtin_fmaf(qa.x, K, nLf));
    float e1 = fexp2(__builtin_fmaf(qa.y, K, nLf));
    float e2 = fexp2(__builtin_fmaf(qa.z, K, nLf));
    float e3 = fexp2(__builtin_fmaf(qa.w, K, nLf));
    float e4 = fexp2(__builtin_fmaf(qb,   K, nLf));
    float s = e0 * a_cur;
    s = __builtin_fmaf(e1, p0, s);
    s = __builtin_fmaf(e2, p1, s);
    s = __builtin_fmaf(e3, p2, s);
    s = __builtin_fmaf(e4, p3, s);
    a_cur = s;
    cacc += Lnext;
    ap[(t & 1) * SD + wroff] = s;
    const int xb = ((__float_as_int(R) >> 23) & 0xFF) - 127;
    Lnext = xb >> 2;                    // damped controller: lag 1, gain 1/4
    nLf = (float)(-Lnext);
    if (((t & 3) == 0) && (u == 0))     // publish progress for warmers
      __hip_atomic_store(&prog[n * 64], t, __ATOMIC_RELAXED, __HIP_MEMORY_SCOPE_AGENT);
    asm volatile("s_waitcnt lgkmcnt(0)\n\ts_barrier" ::: "memory");
  };

#define PRO(cc)                                                             \
  const float* P##cc = sn + (size_t)((cc) < T ? (cc) : T - 1) * tstr;       \
  f4a qa##cc = *(const f4a*)P##cc;                                          \
  float qb##cc = P##cc[4];                                                  \
  P##cc += str4;
  PRO(0) PRO(1) PRO(2) PRO(3)
#undef PRO

  __syncthreads();

#define RL(cc)                                                              \
  qa##cc = *(const f4a*)P##cc;                                              \
  qb##cc = P##cc[4];                                                        \
  P##cc += str4;

  int t = 0;
  for (; t + 8 <= T; t += 4) {
    CP(t + 0, qa0, qb0); RL(0)
    CP(t + 1, qa1, qb1); RL(1)
    CP(t + 2, qa2, qb2); RL(2)
    CP(t + 3, qa3, qb3); RL(3)
  }
#undef RL

#define EPI1(cc)                                                            \
  if (t + (cc) < T) {                                                       \
    CP(t + (cc), qa##cc, qb##cc);                                           \
    if (t + 4 + (cc) < T) { qa##cc = *(const f4a*)P##cc; qb##cc = P##cc[4]; }\
  }
  EPI1(0) EPI1(1) EPI1(2) EPI1(3)
#undef EPI1
  t += 4;
#define EPI2(cc) if (t + (cc) < T) CP(t + (cc), qa##cc, qb##cc);
  EPI2(0) EPI2(1) EPI2(2) EPI2(3)
#undef EPI2

  if (u == 0)
    __hip_atomic_store(&prog[n * 64], DONE_S, __ATOMIC_RELAXED, __HIP_MEMORY_SCOPE_AGENT);

  float v = a_cur;
#pragma unroll
  for (int d = 1; d < 64; d <<= 1) v += __shfl_xor(v, d, 64);
  if (lane == 0) red[wid] = v;
  __syncthreads();
  if (u == 0) {
    float ssum = red[0];
#pragma unroll
    for (int i = 1; i < 16; ++i) ssum += red[i];
    out[n] = LN2 * ((float)cacc + flog2(ssum));
  }
}

extern "C" void kernel_launch(void* const* d_in, const int* in_sizes, int n_in,
                              void* d_out, int out_size, void* d_ws, size_t ws_size,
                              hipStream_t stream) {
  const float* scores = (const float*)d_in[0];
  float* out = (float*)d_out;
  int* prog = (int*)d_ws;
  const long long tot = (long long)in_sizes[0];
  const int T = (int)(tot / ((long long)NB * CD));
  init_prog<<<dim3(1), dim3(64), 0, stream>>>(prog);
  ctc_logz<<<dim3(128), dim3(1024), 0, stream>>>(scores, out, prog, T);
}